// Round 17
// baseline (385.738 us; speedup 1.0000x reference)
//
#include <hip/hip_runtime.h>
#include <stdint.h>

// ---------------------------------------------------------------------------
// Fused LSTM cell, round 17: r11 (best, 196us) + ABLATION PROBES.
//  Correct path (unchanged r11): prep_all -> lstm_main.
//  Probes (extra dispatches, output-safe):
//   lstm_epi  : BEFORE main; fake acc -> exact r11 C-load + gate VALU + NT
//               stores to d_out (main overwrites it afterwards). Time = E.
//   lstm_gemm : r11 main minus C minus epilogue; acc kept live via asm.
//               Time = G. Decomposes main's 158us: G vs E vs overlap.
// ---------------------------------------------------------------------------

typedef short bf16x8 __attribute__((ext_vector_type(8)));
typedef float f32x4  __attribute__((ext_vector_type(4)));

#define HDIM   256
#define INDIM  100
#define NROWS  131072
// d_ws layout (ushort offsets): Bt @0 (768 KiB), xb @1 MiB, hb @34 MiB
#define BT_OFF 0
#define XB_OFF (1048576 / 2)
#define HB_OFF (35651584 / 2)
#define ABUF(b) ((b) * 8192)
#define BBUF(b) (24576 + (b) * 16384)

__device__ __forceinline__ float fexp(float x) {
  return __builtin_amdgcn_exp2f(x * 1.44269504088896340736f);
}
__device__ __forceinline__ float frcp(float x) { return __builtin_amdgcn_rcpf(x); }
__device__ __forceinline__ float sigm(float x) { return frcp(1.0f + fexp(-x)); }
__device__ __forceinline__ float tanh_fast(float x) {
  return 1.0f - 2.0f * frcp(1.0f + fexp(2.0f * x));
}
__device__ __forceinline__ unsigned short f2bf_rne(float f) {
  union { float f; uint32_t u; } v; v.f = f;
  return (unsigned short)((v.u + 0x7FFFu + ((v.u >> 16) & 1u)) >> 16);
}
__device__ __forceinline__ void gl16(const void* g, void* l) {
  __builtin_amdgcn_global_load_lds(
      (const __attribute__((address_space(1))) unsigned int*)g,
      (__attribute__((address_space(3))) unsigned int*)l, 16, 0, 0);
}
#define VMW(N) asm volatile("s_waitcnt vmcnt(" #N ")" ::: "memory")

// ---- prep: 3 jobs (unchanged) ---------------------------------------------
__global__ void prep_all(const float* __restrict__ X, const float* __restrict__ Hin,
                         const float* __restrict__ Wx, const float* __restrict__ Wh,
                         const float* __restrict__ bxp, const float* __restrict__ bhp,
                         unsigned short* __restrict__ ws) {
  const int b = blockIdx.x, tid = threadIdx.x;
  if (b < 8192) {                        // ---- x -> xb[131072][128] ----
    const int t   = b * 256 + tid;
    const int row = t >> 4, k0 = (t & 15) * 8;
    const float* xp = X + (size_t)row * INDIM;
    float4 lo = make_float4(0.f, 0.f, 0.f, 0.f);
    float4 hi = make_float4(0.f, 0.f, 0.f, 0.f);
    if (k0 + 4 <= INDIM) lo = *reinterpret_cast<const float4*>(xp + k0);
    if (k0 + 8 <= INDIM) hi = *reinterpret_cast<const float4*>(xp + k0 + 4);
    float va[8] = {lo.x, lo.y, lo.z, lo.w, hi.x, hi.y, hi.z, hi.w};
    unsigned short o[8];
#pragma unroll
    for (int e = 0; e < 8; ++e) {
      const int k = k0 + e;
      const float f = (k < INDIM) ? va[e] : (k == 127 ? 1.0f : 0.0f);
      o[e] = f2bf_rne(f);
    }
    *reinterpret_cast<bf16x8*>(ws + XB_OFF + (size_t)row * 128 + k0) =
        *reinterpret_cast<bf16x8*>(o);
  } else if (b < 24576) {                // ---- h -> hb[131072][256] ----
    const int t   = (b - 8192) * 256 + tid;
    const int row = t >> 5, k0 = (t & 31) * 8;
    const float* hp = Hin + (size_t)row * HDIM + k0;
    const float4 lo = *reinterpret_cast<const float4*>(hp);
    const float4 hi = *reinterpret_cast<const float4*>(hp + 4);
    unsigned short o[8] = {f2bf_rne(lo.x), f2bf_rne(lo.y), f2bf_rne(lo.z),
                           f2bf_rne(lo.w), f2bf_rne(hi.x), f2bf_rne(hi.y),
                           f2bf_rne(hi.z), f2bf_rne(hi.w)};
    *reinterpret_cast<bf16x8*>(ws + HB_OFF + (size_t)row * 256 + k0) =
        *reinterpret_cast<bf16x8*>(o);
  } else {                               // ---- W -> Bt blob (bias @ k127) --
    const int unit = (b - 24576) * 4 + (tid >> 6);   // 0..767
    const int lane = tid & 63;
    const int kst  = unit % 12;
    const int fidb = unit / 12;
    const int bn   = fidb >> 3, fid = fidb & 7;
    const int g    = fid >> 1,  wc  = fid & 1;
    const int wcol = g * HDIM + bn * 32 + wc * 16 + (lane & 15);
    const int kb   = kst * 32 + (lane >> 4) * 8;
    unsigned short v[8];
#pragma unroll
    for (int e = 0; e < 8; ++e) {
      const int k = kb + e;              // 0..383
      float f = 0.0f;
      if (k < INDIM)     f = Wx[(size_t)k * 1024 + wcol];
      else if (k == 127) f = bxp[wcol] + bhp[wcol];
      else if (k >= 128) f = Wh[(size_t)(k - 128) * 1024 + wcol];
      v[e] = f2bf_rne(f);
    }
    *reinterpret_cast<bf16x8*>(ws + BT_OFF + (size_t)unit * 512 + lane * 8) =
        *reinterpret_cast<bf16x8*>(v);
  }
}

// ---- PROBE: epilogue only (runs BEFORE main; main overwrites d_out) -------
__global__ __launch_bounds__(512, 2)
void lstm_epi(const float* __restrict__ Cin, float* __restrict__ out)
{
  const int tid  = threadIdx.x;
  const int orig = blockIdx.x;
  const int lg   = ((orig & 7) << 9) | (orig >> 3);
  const int mt   = lg >> 2;
  const int bnn  = lg & 3;
  const int lane = tid & 63;
  const int l15  = lane & 15;
  const int kq   = lane >> 4;
  const int wid  = tid >> 6;
  const int wr   = wid >> 2;
  const int wcq  = wid & 3;
  const int ch   = bnn * 64 + wcq * 16 + l15;

  // fake, tid-derived accumulators (not constant-foldable)
  const float base = (float)((tid * 2654435761u + orig * 40503u) & 1023) *
                     0.003f - 1.5f;
  float cvv[4][4];
  const float* cb = Cin + ((size_t)mt * 128 + wr * 64 + kq * 4) * HDIM + ch;
#pragma unroll
  for (int m = 0; m < 4; ++m)
#pragma unroll
    for (int e = 0; e < 4; ++e)
      cvv[m][e] = __builtin_nontemporal_load(cb + (size_t)(m * 16 + e) * HDIM);

  float* op  = out + ((size_t)mt * 128 + wr * 64 + kq * 4) * HDIM + ch;
  float* op2 = op + (size_t)NROWS * HDIM;
#pragma unroll
  for (int m = 0; m < 4; ++m) {
#pragma unroll
    for (int e = 0; e < 4; ++e) {
      const float pi = base + m * 0.11f + e * 0.07f;
      const float pf = base * 0.9f + m * 0.05f - e * 0.03f;
      const float pg = base * 1.1f - m * 0.02f + e * 0.09f;
      const float po = base * 0.8f + m * 0.04f + e * 0.01f;
      const float ig = sigm(pi), fg = sigm(pf);
      const float gg = tanh_fast(pg), og = sigm(po);
      const float co = fg * cvv[m][e] + ig * gg;
      const float ho = og * tanh_fast(co);
      __builtin_nontemporal_store(co, op  + (size_t)(m * 16 + e) * HDIM);
      __builtin_nontemporal_store(ho, op2 + (size_t)(m * 16 + e) * HDIM);
    }
  }
}

// ---- PROBE: GEMM pipeline only (no C, no epilogue; acc kept live) ---------
__global__ __launch_bounds__(512, 2)
void lstm_gemm(const unsigned short* __restrict__ ws)
{
  __shared__ unsigned char smem[73728];

  const int tid  = threadIdx.x;
  const int orig = blockIdx.x;
  const int lg   = ((orig & 7) << 9) | (orig >> 3);
  const int mt   = lg >> 2;
  const int bnn  = lg & 3;
  const int lane = tid & 63;
  const int l15  = lane & 15;
  const int kq   = lane >> 4;
  const int wid  = tid >> 6;
  const int wr   = wid >> 2;
  const int sx   = (l15 >> 1) & 3;
  const int wcq  = wid & 3;

  const unsigned short* xb = ws + XB_OFF;
  const unsigned short* hb = ws + HB_OFF;
  const unsigned short* Bt = ws + BT_OFF;

  const int ci = wid * 64 + lane;
  const int r  = ci >> 2;
  const int sc = (ci & 3) ^ ((r >> 1) & 3);
  const unsigned short* xsrc = xb + (size_t)(mt * 128 + r) * 128 + sc * 8;
  const unsigned short* hsrc = hb + (size_t)(mt * 128 + r) * 256 + sc * 8;
  const unsigned short* bsrc[2];
#pragma unroll
  for (int j = 0; j < 2; ++j) {
    const int u  = wid * 2 + j;
    const int gu = (bnn * 2 + (u >> 3)) * 8 + (u & 7);
    bsrc[j] = Bt + (size_t)gu * 12 * 512 + lane * 8;
  }
  const int adst = wid * 1024;
  const int bd0  = (wid * 2 + 0) * 1024;
  const int bd1  = (wid * 2 + 1) * 1024;

  f32x4 acc[4][4];
#pragma unroll
  for (int m = 0; m < 4; ++m)
#pragma unroll
    for (int g = 0; g < 4; ++g)
#pragma unroll
      for (int e = 0; e < 4; ++e) acc[m][g][e] = 0.0f;

  auto STAGE = [&](int T) {
    char* Ad = (char*)smem + ABUF(T % 3);
    char* Bd = (char*)smem + BBUF(T % 3);
    if (T < 4) gl16(xsrc + T * 32, Ad + adst);
    else       gl16(hsrc + (T - 4) * 32, Ad + adst);
    gl16(bsrc[0] + T * 512, Bd + bd0);
    gl16(bsrc[1] + T * 512, Bd + bd1);
  };
  auto COMPUTE = [&](int S) {
    const unsigned short* Ab = (const unsigned short*)(smem + ABUF(S % 3));
    const unsigned short* Bb = (const unsigned short*)(smem + BBUF(S % 3));
    bf16x8 afr[4], bfr[4];
#pragma unroll
    for (int m = 0; m < 4; ++m)
      afr[m] = *reinterpret_cast<const bf16x8*>(
          Ab + (wr * 64 + m * 16 + l15) * 32 + ((kq ^ sx) * 8));
#pragma unroll
    for (int g = 0; g < 4; ++g) {
      const int ub = (wcq >> 1) * 8 + g * 2 + (wcq & 1);
      bfr[g] = *reinterpret_cast<const bf16x8*>(Bb + ub * 512 + lane * 8);
    }
    __builtin_amdgcn_s_setprio(1);
#pragma unroll
    for (int m = 0; m < 4; ++m)
#pragma unroll
      for (int g = 0; g < 4; ++g)
        acc[m][g] = __builtin_amdgcn_mfma_f32_16x16x32_bf16(
            afr[m], bfr[g], acc[m][g], 0, 0, 0);
    __builtin_amdgcn_s_setprio(0);
  };

  STAGE(0);
  STAGE(1);
#define STEP(S, KN)                        \
  do {                                     \
    VMW(KN);                               \
    __builtin_amdgcn_s_barrier();          \
    if ((S) + 2 < 12) STAGE((S) + 2);      \
    COMPUTE(S);                            \
  } while (0)
  STEP(0, 3);  STEP(1, 3);  STEP(2, 3);  STEP(3, 3);
  STEP(4, 3);  STEP(5, 3);  STEP(6, 3);  STEP(7, 3);
  STEP(8, 3);  STEP(9, 3);  STEP(10, 3); STEP(11, 0);
#undef STEP

  // keep the whole MFMA chain live without any stores (rule #17)
#pragma unroll
  for (int m = 0; m < 4; ++m)
#pragma unroll
    for (int g = 0; g < 4; ++g)
#pragma unroll
      for (int e = 0; e < 4; ++e)
        asm volatile("" :: "v"(acc[m][g][e]));
}

// ---- main (byte-identical to round 11) ------------------------------------
__global__ __launch_bounds__(512, 2)
void lstm_main(const unsigned short* __restrict__ ws,
               const float* __restrict__ Cin, float* __restrict__ out)
{
  __shared__ unsigned char smem[73728];  // 3 x (8K A + 16K B)

  const int tid  = threadIdx.x;
  const int orig = blockIdx.x;           // 0..4095 (%8==0 -> bijective)
  const int lg   = ((orig & 7) << 9) | (orig >> 3);
  const int mt   = lg >> 2;              // M tile 0..1023 (128 rows)
  const int bnn  = lg & 3;               // N tile 0..3 (64 H-cols)

  const int lane = tid & 63;
  const int l15  = lane & 15;
  const int kq   = lane >> 4;
  const int wid  = tid >> 6;             // 0..7
  const int wr   = wid >> 2;             // 0..1: 64-row group
  const int wcq  = wid & 3;              // 0..3: 16-hcol quarter
  const int ch   = bnn * 64 + wcq * 16 + l15;
  const int sx   = (l15 >> 1) & 3;       // read-side XOR (== (row>>1)&3)

  const unsigned short* xb = ws + XB_OFF;
  const unsigned short* hb = ws + HB_OFF;
  const unsigned short* Bt = ws + BT_OFF;

  const int ci = wid * 64 + lane;                // 0..511
  const int r  = ci >> 2;                        // tile row 0..127
  const int sc = (ci & 3) ^ ((r >> 1) & 3);      // pre-swizzled chunk
  const unsigned short* xsrc = xb + (size_t)(mt * 128 + r) * 128 + sc * 8;
  const unsigned short* hsrc = hb + (size_t)(mt * 128 + r) * 256 + sc * 8;

  const unsigned short* bsrc[2];
#pragma unroll
  for (int j = 0; j < 2; ++j) {
    const int u  = wid * 2 + j;                  // local unit 0..15
    const int gu = (bnn * 2 + (u >> 3)) * 8 + (u & 7);
    bsrc[j] = Bt + (size_t)gu * 12 * 512 + lane * 8;
  }
  const int adst = wid * 1024;
  const int bd0  = (wid * 2 + 0) * 1024;
  const int bd1  = (wid * 2 + 1) * 1024;

  f32x4 acc[4][4];
#pragma unroll
  for (int m = 0; m < 4; ++m)
#pragma unroll
    for (int g = 0; g < 4; ++g)
#pragma unroll
      for (int e = 0; e < 4; ++e) acc[m][g][e] = 0.0f;

  float cvv[4][4];

  auto STAGE = [&](int T) {
    char* Ad = (char*)smem + ABUF(T % 3);
    char* Bd = (char*)smem + BBUF(T % 3);
    if (T < 4) gl16(xsrc + T * 32, Ad + adst);
    else       gl16(hsrc + (T - 4) * 32, Ad + adst);
    gl16(bsrc[0] + T * 512, Bd + bd0);
    gl16(bsrc[1] + T * 512, Bd + bd1);
  };

  auto COMPUTE = [&](int S) {
    const unsigned short* Ab = (const unsigned short*)(smem + ABUF(S % 3));
    const unsigned short* Bb = (const unsigned short*)(smem + BBUF(S % 3));
    bf16x8 afr[4], bfr[4];
#pragma unroll
    for (int m = 0; m < 4; ++m)
      afr[m] = *reinterpret_cast<const bf16x8*>(
          Ab + (wr * 64 + m * 16 + l15) * 32 + ((kq ^ sx) * 8));
#pragma unroll
    for (int g = 0; g < 4; ++g) {
      const int ub = (wcq >> 1) * 8 + g * 2 + (wcq & 1);
      bfr[g] = *reinterpret_cast<const bf16x8*>(Bb + ub * 512 + lane * 8);
    }
    __builtin_amdgcn_s_setprio(1);
#pragma unroll
    for (int m = 0; m < 4; ++m)
#pragma unroll
      for (int g = 0; g < 4; ++g)
        acc[m][g] = __builtin_amdgcn_mfma_f32_16x16x32_bf16(
            afr[m], bfr[g], acc[m][g], 0, 0, 0);
    __builtin_amdgcn_s_setprio(0);
  };

  STAGE(0);
  STAGE(1);

#define STEP(S, KN)                                               \
  do {                                                            \
    VMW(KN);                                                      \
    __builtin_amdgcn_s_barrier();                                 \
    if ((S) + 2 < 12) STAGE((S) + 2);                             \
    if ((S) == 9) {                                               \
      const float* cb =                                           \
          Cin + ((size_t)mt * 128 + wr * 64 + kq * 4) * HDIM + ch;\
      _Pragma("unroll")                                           \
      for (int m = 0; m < 4; ++m)                                 \
        _Pragma("unroll")                                         \
        for (int e = 0; e < 4; ++e)                               \
          cvv[m][e] = __builtin_nontemporal_load(                 \
              cb + (size_t)(m * 16 + e) * HDIM);                  \
    }                                                             \
    COMPUTE(S);                                                   \
  } while (0)

  STEP(0, 3);  STEP(1, 3);  STEP(2, 3);  STEP(3, 3);
  STEP(4, 3);  STEP(5, 3);  STEP(6, 3);  STEP(7, 3);
  STEP(8, 3);  STEP(9, 3);  STEP(10, 19); STEP(11, 16);
#undef STEP

  VMW(0);

  float* op  = out + ((size_t)mt * 128 + wr * 64 + kq * 4) * HDIM + ch;
  float* op2 = op + (size_t)NROWS * HDIM;
#pragma unroll
  for (int m = 0; m < 4; ++m) {
#pragma unroll
    for (int e = 0; e < 4; ++e) {
      const float pi = acc[m][0][e];
      const float pf = acc[m][1][e];
      const float pg = acc[m][2][e];
      const float po = acc[m][3][e];
      const float ig = sigm(pi), fg = sigm(pf);
      const float gg = tanh_fast(pg), og = sigm(po);
      const float co = fg * cvv[m][e] + ig * gg;
      const float ho = og * tanh_fast(co);
      __builtin_nontemporal_store(co, op  + (size_t)(m * 16 + e) * HDIM);
      __builtin_nontemporal_store(ho, op2 + (size_t)(m * 16 + e) * HDIM);
    }
  }
}

extern "C" void kernel_launch(void* const* d_in, const int* in_sizes, int n_in,
                              void* d_out, int out_size, void* d_ws, size_t ws_size,
                              hipStream_t stream) {
  const float* x  = (const float*)d_in[0];
  const float* C  = (const float*)d_in[1];
  const float* h  = (const float*)d_in[2];
  const float* Wx = (const float*)d_in[3];
  const float* Wh = (const float*)d_in[4];
  const float* bx = (const float*)d_in[5];
  const float* bh = (const float*)d_in[6];
  float* o = (float*)d_out;
  unsigned short* ws = (unsigned short*)d_ws;   // ~98 MiB used

  prep_all<<<dim3(24768), dim3(256), 0, stream>>>(x, h, Wx, Wh, bx, bh, ws);
  // probes (output-safe: epi writes d_out BEFORE main overwrites it;
  // gemm probe writes nothing)
  lstm_epi <<<dim3(4096), dim3(512), 0, stream>>>(C, o);
  lstm_gemm<<<dim3(4096), dim3(512), 0, stream>>>(ws);
  // correct path
  lstm_main<<<dim3(4096), dim3(512), 0, stream>>>(ws, C, o);
}

// Round 18
// 235.385 us; speedup vs baseline: 1.6387x; 1.6387x over previous
//
#include <hip/hip_runtime.h>
#include <stdint.h>

// ---------------------------------------------------------------------------
// Fused LSTM cell, round 18: r10 geometry + 2-deep LDS -> 4-5 blocks/CU.
//  Hypothesis (from r17 ablation): GEMM phase is additively serialized
//  (every pipe 25-50%, none saturated); more INDEPENDENT blocks per CU
//  interleave one block's ds_read/VALU phase with another's MFMA phase.
//  prep_all: xb[131072][128] bf16 (pad, k127=1.0), hb[131072][256] bf16,
//            Bt fragment blob (bias @ k127). Unchanged.
//  lstm_main: 256 thr (4 waves: 2 wr x 2 wc), tile 128 x 128 gate-cols,
//    12 stages BK=32, 4 gl_lds/wave/stage (2A+2B, homogeneous FIFO),
//    2-deep LDS dbuf (32 KiB) -> 5 blocks fit in 160K LDS. Step:
//    VMW(4); bar; COMPUTE(S); bar; STAGE(S+2). Overwrite-safe: compute's
//    ds_reads are register-captured (lgkmcnt before MFMA) before bar2.
//    C-tail FIFO-exact: VMW(20)/VMW(20)/VMW(0). VGPR ~72 (no spill; the
//    r13 attempt at this hypothesis died on launch_bounds(512,6) -> 40 VGPR).
// ---------------------------------------------------------------------------

typedef short bf16x8 __attribute__((ext_vector_type(8)));
typedef float f32x4  __attribute__((ext_vector_type(4)));

#define HDIM   256
#define INDIM  100
#define NROWS  131072
// d_ws layout (ushort offsets): Bt @0 (768 KiB), xb @1 MiB, hb @34 MiB
#define BT_OFF 0
#define XB_OFF (1048576 / 2)
#define HB_OFF (35651584 / 2)
#define ABUF(b) ((b) * 8192)
#define BBUF(b) (16384 + (b) * 8192)

__device__ __forceinline__ float fexp(float x) {
  return __builtin_amdgcn_exp2f(x * 1.44269504088896340736f);
}
__device__ __forceinline__ float frcp(float x) { return __builtin_amdgcn_rcpf(x); }
__device__ __forceinline__ float sigm(float x) { return frcp(1.0f + fexp(-x)); }
__device__ __forceinline__ float tanh_fast(float x) {
  return 1.0f - 2.0f * frcp(1.0f + fexp(2.0f * x));
}
__device__ __forceinline__ unsigned short f2bf_rne(float f) {
  union { float f; uint32_t u; } v; v.f = f;
  return (unsigned short)((v.u + 0x7FFFu + ((v.u >> 16) & 1u)) >> 16);
}
__device__ __forceinline__ void gl16(const void* g, void* l) {
  __builtin_amdgcn_global_load_lds(
      (const __attribute__((address_space(1))) unsigned int*)g,
      (__attribute__((address_space(3))) unsigned int*)l, 16, 0, 0);
}
#define VMW(N) asm volatile("s_waitcnt vmcnt(" #N ")" ::: "memory")

// ---- prep: 3 jobs (unchanged) ---------------------------------------------
__global__ void prep_all(const float* __restrict__ X, const float* __restrict__ Hin,
                         const float* __restrict__ Wx, const float* __restrict__ Wh,
                         const float* __restrict__ bxp, const float* __restrict__ bhp,
                         unsigned short* __restrict__ ws) {
  const int b = blockIdx.x, tid = threadIdx.x;
  if (b < 8192) {                        // ---- x -> xb[131072][128] ----
    const int t   = b * 256 + tid;
    const int row = t >> 4, k0 = (t & 15) * 8;
    const float* xp = X + (size_t)row * INDIM;
    float4 lo = make_float4(0.f, 0.f, 0.f, 0.f);
    float4 hi = make_float4(0.f, 0.f, 0.f, 0.f);
    if (k0 + 4 <= INDIM) lo = *reinterpret_cast<const float4*>(xp + k0);
    if (k0 + 8 <= INDIM) hi = *reinterpret_cast<const float4*>(xp + k0 + 4);
    float va[8] = {lo.x, lo.y, lo.z, lo.w, hi.x, hi.y, hi.z, hi.w};
    unsigned short o[8];
#pragma unroll
    for (int e = 0; e < 8; ++e) {
      const int k = k0 + e;
      const float f = (k < INDIM) ? va[e] : (k == 127 ? 1.0f : 0.0f);
      o[e] = f2bf_rne(f);
    }
    *reinterpret_cast<bf16x8*>(ws + XB_OFF + (size_t)row * 128 + k0) =
        *reinterpret_cast<bf16x8*>(o);
  } else if (b < 24576) {                // ---- h -> hb[131072][256] ----
    const int t   = (b - 8192) * 256 + tid;
    const int row = t >> 5, k0 = (t & 31) * 8;
    const float* hp = Hin + (size_t)row * HDIM + k0;
    const float4 lo = *reinterpret_cast<const float4*>(hp);
    const float4 hi = *reinterpret_cast<const float4*>(hp + 4);
    unsigned short o[8] = {f2bf_rne(lo.x), f2bf_rne(lo.y), f2bf_rne(lo.z),
                           f2bf_rne(lo.w), f2bf_rne(hi.x), f2bf_rne(hi.y),
                           f2bf_rne(hi.z), f2bf_rne(hi.w)};
    *reinterpret_cast<bf16x8*>(ws + HB_OFF + (size_t)row * 256 + k0) =
        *reinterpret_cast<bf16x8*>(o);
  } else {                               // ---- W -> Bt blob (bias @ k127) --
    const int unit = (b - 24576) * 4 + (tid >> 6);   // 0..767
    const int lane = tid & 63;
    const int kst  = unit % 12;
    const int fidb = unit / 12;
    const int bn   = fidb >> 3, fid = fidb & 7;
    const int g    = fid >> 1,  wc  = fid & 1;
    const int wcol = g * HDIM + bn * 32 + wc * 16 + (lane & 15);
    const int kb   = kst * 32 + (lane >> 4) * 8;
    unsigned short v[8];
#pragma unroll
    for (int e = 0; e < 8; ++e) {
      const int k = kb + e;              // 0..383
      float f = 0.0f;
      if (k < INDIM)     f = Wx[(size_t)k * 1024 + wcol];
      else if (k == 127) f = bxp[wcol] + bhp[wcol];
      else if (k >= 128) f = Wh[(size_t)(k - 128) * 1024 + wcol];
      v[e] = f2bf_rne(f);
    }
    *reinterpret_cast<bf16x8*>(ws + BT_OFF + (size_t)unit * 512 + lane * 8) =
        *reinterpret_cast<bf16x8*>(v);
  }
}

// ---- main -----------------------------------------------------------------
__global__ __launch_bounds__(256, 4)
void lstm_main(const unsigned short* __restrict__ ws,
               const float* __restrict__ Cin, float* __restrict__ out)
{
  __shared__ unsigned char smem[32768];  // A dbuf 2x8K @0, B dbuf 2x8K @16K

  const int tid  = threadIdx.x;
  const int orig = blockIdx.x;           // 0..8191 (%8==0 -> bijective)
  const int lg   = ((orig & 7) << 10) | (orig >> 3);
  const int mt   = lg >> 3;              // M tile 0..1023 (128 rows)
  const int bn   = lg & 7;               // N tile 0..7 (32 H-cols)

  const int lane = tid & 63;
  const int l15  = lane & 15;
  const int kq   = lane >> 4;
  const int wid  = tid >> 6;             // 0..3
  const int wr   = wid >> 1;             // 0..1: 64-row group
  const int wc   = wid & 1;              // 0..1: 16-hcol half
  const int ch   = bn * 32 + wc * 16 + l15;
  const int sx   = (l15 >> 1) & 3;       // read-side XOR (== (row>>1)&3)

  const unsigned short* xb = ws + XB_OFF;
  const unsigned short* hb = ws + HB_OFF;
  const unsigned short* Bt = ws + BT_OFF;

  // staging sources: per wave 2 A-units + 2 B-units per stage
  const unsigned short* xsrc[2];
  const unsigned short* hsrc[2];
  const unsigned short* bsrc[2];
#pragma unroll
  for (int j = 0; j < 2; ++j) {
    const int ci  = (wid * 2 + j) * 64 + lane;     // 0..511
    const int r   = ci >> 2;                       // tile row 0..127
    const int sc  = (ci & 3) ^ ((r >> 1) & 3);     // pre-swizzled chunk
    xsrc[j] = xb + (size_t)(mt * 128 + r) * 128 + sc * 8;
    hsrc[j] = hb + (size_t)(mt * 128 + r) * 256 + sc * 8;
    bsrc[j] = Bt + (size_t)((bn * 8 + wid * 2 + j) * 12) * 512 + lane * 8;
  }
  const int au0 = (wid * 2 + 0) * 1024;  // wave-uniform LDS sub-offsets
  const int au1 = (wid * 2 + 1) * 1024;

  f32x4 acc[4][4];
#pragma unroll
  for (int m = 0; m < 4; ++m)
#pragma unroll
    for (int g = 0; g < 4; ++g)
#pragma unroll
      for (int e = 0; e < 4; ++e) acc[m][g][e] = 0.0f;

  float cvv[4][4];

  auto STAGE = [&](int T) {
    char* Ad = (char*)smem + ABUF(T & 1);
    char* Bd = (char*)smem + BBUF(T & 1);
    if (T < 4) {
      gl16(xsrc[0] + T * 32, Ad + au0);
      gl16(xsrc[1] + T * 32, Ad + au1);
    } else {
      gl16(hsrc[0] + (T - 4) * 32, Ad + au0);
      gl16(hsrc[1] + (T - 4) * 32, Ad + au1);
    }
    gl16(bsrc[0] + T * 512, Bd + au0);
    gl16(bsrc[1] + T * 512, Bd + au1);
  };

  auto COMPUTE = [&](int S) {
    const unsigned short* Ab = (const unsigned short*)(smem + ABUF(S & 1));
    const unsigned short* Bb = (const unsigned short*)(smem + BBUF(S & 1));
    bf16x8 afr[4], bfr[4];
#pragma unroll
    for (int m = 0; m < 4; ++m)
      afr[m] = *reinterpret_cast<const bf16x8*>(
          Ab + (wr * 64 + m * 16 + l15) * 32 + ((kq ^ sx) * 8));
#pragma unroll
    for (int g = 0; g < 4; ++g)
      bfr[g] = *reinterpret_cast<const bf16x8*>(
          Bb + (g * 2 + wc) * 512 + lane * 8);
    __builtin_amdgcn_s_setprio(1);
#pragma unroll
    for (int m = 0; m < 4; ++m)
#pragma unroll
      for (int g = 0; g < 4; ++g)
        acc[m][g] = __builtin_amdgcn_mfma_f32_16x16x32_bf16(
            afr[m], bfr[g], acc[m][g], 0, 0, 0);
    __builtin_amdgcn_s_setprio(0);
  };

  // prologue: 2 stages (8 gl_lds) in flight
  STAGE(0);
  STAGE(1);

  // FIFO (4 gl_lds/stage/wave): at top of step S, VMW(N) guarantees stage S
  // landed, N = ops issued after it. Steady: S(S+1) only -> VMW(4).
  // C (16 loads) issued at end of step 8 after STAGE(10):
  //   step 9 top: after S(9) = S(10)4+C16 -> VMW(20)
  //   step 10 top: after S(10) = C16+S(11)4 -> VMW(20)
  //   step 11 top: after S(11) = 0 -> VMW(0) (drains C as well).
  // bar2 (after COMPUTE) makes the 2-deep overwrite safe: every wave's
  // ds_reads are register-captured (compiler lgkmcnt before MFMA) before it.
#define STEP(S, KN)                                               \
  do {                                                            \
    VMW(KN);                                                      \
    __builtin_amdgcn_s_barrier();                                 \
    COMPUTE(S);                                                   \
    if ((S) + 2 < 12) {                                           \
      __builtin_amdgcn_s_barrier();                               \
      STAGE((S) + 2);                                             \
    }                                                             \
    if ((S) == 8) {                                               \
      const float* cb =                                           \
          Cin + ((size_t)mt * 128 + wr * 64 + kq * 4) * HDIM + ch;\
      _Pragma("unroll")                                           \
      for (int m = 0; m < 4; ++m)                                 \
        _Pragma("unroll")                                         \
        for (int e = 0; e < 4; ++e)                               \
          cvv[m][e] = __builtin_nontemporal_load(                 \
              cb + (size_t)(m * 16 + e) * HDIM);                  \
    }                                                             \
  } while (0)

  STEP(0, 4);  STEP(1, 4);  STEP(2, 4);  STEP(3, 4);
  STEP(4, 4);  STEP(5, 4);  STEP(6, 4);  STEP(7, 4);
  STEP(8, 4);  STEP(9, 20); STEP(10, 20); STEP(11, 0);
#undef STEP

  // ---- epilogue: bias folded in acc; lane-local gate combine -------------
  float* op  = out + ((size_t)mt * 128 + wr * 64 + kq * 4) * HDIM + ch;
  float* op2 = op + (size_t)NROWS * HDIM;
#pragma unroll
  for (int m = 0; m < 4; ++m) {
#pragma unroll
    for (int e = 0; e < 4; ++e) {
      const float pi = acc[m][0][e];
      const float pf = acc[m][1][e];
      const float pg = acc[m][2][e];
      const float po = acc[m][3][e];
      const float ig = sigm(pi), fg = sigm(pf);
      const float gg = tanh_fast(pg), og = sigm(po);
      const float co = fg * cvv[m][e] + ig * gg;
      const float ho = og * tanh_fast(co);
      __builtin_nontemporal_store(co, op  + (size_t)(m * 16 + e) * HDIM);
      __builtin_nontemporal_store(ho, op2 + (size_t)(m * 16 + e) * HDIM);
    }
  }
}

extern "C" void kernel_launch(void* const* d_in, const int* in_sizes, int n_in,
                              void* d_out, int out_size, void* d_ws, size_t ws_size,
                              hipStream_t stream) {
  const float* x  = (const float*)d_in[0];
  const float* C  = (const float*)d_in[1];
  const float* h  = (const float*)d_in[2];
  const float* Wx = (const float*)d_in[3];
  const float* Wh = (const float*)d_in[4];
  const float* bx = (const float*)d_in[5];
  const float* bh = (const float*)d_in[6];
  float* o = (float*)d_out;
  unsigned short* ws = (unsigned short*)d_ws;   // ~98 MiB used

  prep_all<<<dim3(24768), dim3(256), 0, stream>>>(x, h, Wx, Wh, bx, bh, ws);
  lstm_main<<<dim3(8192), dim3(256), 0, stream>>>(ws, C, o);
}

// Round 19
// 193.509 us; speedup vs baseline: 1.9934x; 1.2164x over previous
//
#include <hip/hip_runtime.h>
#include <stdint.h>

// ---------------------------------------------------------------------------
// Fused LSTM cell, round 19 = round 11 (champion, 196us) restored exactly,
// plus two zero-risk micro-edits:
//   (1) s_setprio removed (T5 measured null-to-negative on non-8-phase GEMM)
//   (2) C-prefetch moved S==9 -> S==7, FIFO re-counted (3...,19,19,3,0):
//       C covered by 3+ compute phases and drained before the epilogue.
//  prep_all: xb[131072][128] bf16 (pad, k127=1.0 bias driver),
//            hb[131072][256] bf16, Bt fragment blob (bias @ k127).
//  lstm_main: 512 thr (8 waves = 2 wr x 4 wcq), tile 128 rows x 256 gatecols,
//    12 stages BK=32, 3 gl_lds/wave/stage (1A+2B homogeneous FIFO),
//    3-deep LDS multibuffer (72 KiB), counted vmcnt, single barrier/step.
// ---------------------------------------------------------------------------

typedef short bf16x8 __attribute__((ext_vector_type(8)));
typedef float f32x4  __attribute__((ext_vector_type(4)));

#define HDIM   256
#define INDIM  100
#define NROWS  131072
// d_ws layout (ushort offsets): Bt @0 (768 KiB), xb @1 MiB, hb @34 MiB
#define BT_OFF 0
#define XB_OFF (1048576 / 2)
#define HB_OFF (35651584 / 2)
#define ABUF(b) ((b) * 8192)
#define BBUF(b) (24576 + (b) * 16384)

__device__ __forceinline__ float fexp(float x) {
  return __builtin_amdgcn_exp2f(x * 1.44269504088896340736f);
}
__device__ __forceinline__ float frcp(float x) { return __builtin_amdgcn_rcpf(x); }
__device__ __forceinline__ float sigm(float x) { return frcp(1.0f + fexp(-x)); }
__device__ __forceinline__ float tanh_fast(float x) {
  return 1.0f - 2.0f * frcp(1.0f + fexp(2.0f * x));
}
__device__ __forceinline__ unsigned short f2bf_rne(float f) {
  union { float f; uint32_t u; } v; v.f = f;
  return (unsigned short)((v.u + 0x7FFFu + ((v.u >> 16) & 1u)) >> 16);
}
__device__ __forceinline__ void gl16(const void* g, void* l) {
  __builtin_amdgcn_global_load_lds(
      (const __attribute__((address_space(1))) unsigned int*)g,
      (__attribute__((address_space(3))) unsigned int*)l, 16, 0, 0);
}
#define VMW(N) asm volatile("s_waitcnt vmcnt(" #N ")" ::: "memory")

// ---- prep: 3 jobs (unchanged) ---------------------------------------------
__global__ void prep_all(const float* __restrict__ X, const float* __restrict__ Hin,
                         const float* __restrict__ Wx, const float* __restrict__ Wh,
                         const float* __restrict__ bxp, const float* __restrict__ bhp,
                         unsigned short* __restrict__ ws) {
  const int b = blockIdx.x, tid = threadIdx.x;
  if (b < 8192) {                        // ---- x -> xb[131072][128] ----
    const int t   = b * 256 + tid;
    const int row = t >> 4, k0 = (t & 15) * 8;
    const float* xp = X + (size_t)row * INDIM;
    float4 lo = make_float4(0.f, 0.f, 0.f, 0.f);
    float4 hi = make_float4(0.f, 0.f, 0.f, 0.f);
    if (k0 + 4 <= INDIM) lo = *reinterpret_cast<const float4*>(xp + k0);
    if (k0 + 8 <= INDIM) hi = *reinterpret_cast<const float4*>(xp + k0 + 4);
    float va[8] = {lo.x, lo.y, lo.z, lo.w, hi.x, hi.y, hi.z, hi.w};
    unsigned short o[8];
#pragma unroll
    for (int e = 0; e < 8; ++e) {
      const int k = k0 + e;
      const float f = (k < INDIM) ? va[e] : (k == 127 ? 1.0f : 0.0f);
      o[e] = f2bf_rne(f);
    }
    *reinterpret_cast<bf16x8*>(ws + XB_OFF + (size_t)row * 128 + k0) =
        *reinterpret_cast<bf16x8*>(o);
  } else if (b < 24576) {                // ---- h -> hb[131072][256] ----
    const int t   = (b - 8192) * 256 + tid;
    const int row = t >> 5, k0 = (t & 31) * 8;
    const float* hp = Hin + (size_t)row * HDIM + k0;
    const float4 lo = *reinterpret_cast<const float4*>(hp);
    const float4 hi = *reinterpret_cast<const float4*>(hp + 4);
    unsigned short o[8] = {f2bf_rne(lo.x), f2bf_rne(lo.y), f2bf_rne(lo.z),
                           f2bf_rne(lo.w), f2bf_rne(hi.x), f2bf_rne(hi.y),
                           f2bf_rne(hi.z), f2bf_rne(hi.w)};
    *reinterpret_cast<bf16x8*>(ws + HB_OFF + (size_t)row * 256 + k0) =
        *reinterpret_cast<bf16x8*>(o);
  } else {                               // ---- W -> Bt blob (bias @ k127) --
    const int unit = (b - 24576) * 4 + (tid >> 6);   // 0..767
    const int lane = tid & 63;
    const int kst  = unit % 12;
    const int fidb = unit / 12;
    const int bn   = fidb >> 3, fid = fidb & 7;
    const int g    = fid >> 1,  wc  = fid & 1;
    const int wcol = g * HDIM + bn * 32 + wc * 16 + (lane & 15);
    const int kb   = kst * 32 + (lane >> 4) * 8;
    unsigned short v[8];
#pragma unroll
    for (int e = 0; e < 8; ++e) {
      const int k = kb + e;              // 0..383
      float f = 0.0f;
      if (k < INDIM)     f = Wx[(size_t)k * 1024 + wcol];
      else if (k == 127) f = bxp[wcol] + bhp[wcol];
      else if (k >= 128) f = Wh[(size_t)(k - 128) * 1024 + wcol];
      v[e] = f2bf_rne(f);
    }
    *reinterpret_cast<bf16x8*>(ws + BT_OFF + (size_t)unit * 512 + lane * 8) =
        *reinterpret_cast<bf16x8*>(v);
  }
}

// ---- main -----------------------------------------------------------------
__global__ __launch_bounds__(512, 2)
void lstm_main(const unsigned short* __restrict__ ws,
               const float* __restrict__ Cin, float* __restrict__ out)
{
  __shared__ unsigned char smem[73728];  // 3 x (8K A + 16K B)

  const int tid  = threadIdx.x;
  const int orig = blockIdx.x;           // 0..4095 (%8==0 -> bijective)
  const int lg   = ((orig & 7) << 9) | (orig >> 3);
  const int mt   = lg >> 2;              // M tile 0..1023 (128 rows)
  const int bnn  = lg & 3;               // N tile 0..3 (64 H-cols)

  const int lane = tid & 63;
  const int l15  = lane & 15;
  const int kq   = lane >> 4;
  const int wid  = tid >> 6;             // 0..7
  const int wr   = wid >> 2;             // 0..1: 64-row group
  const int wcq  = wid & 3;              // 0..3: 16-hcol quarter
  const int ch   = bnn * 64 + wcq * 16 + l15;
  const int sx   = (l15 >> 1) & 3;       // read-side XOR (== (row>>1)&3)

  const unsigned short* xb = ws + XB_OFF;
  const unsigned short* hb = ws + HB_OFF;
  const unsigned short* Bt = ws + BT_OFF;

  // A staging: 1 gl_lds/wave/stage
  const int ci = wid * 64 + lane;                // 0..511
  const int r  = ci >> 2;                        // tile row 0..127
  const int sc = (ci & 3) ^ ((r >> 1) & 3);      // pre-swizzled chunk
  const unsigned short* xsrc = xb + (size_t)(mt * 128 + r) * 128 + sc * 8;
  const unsigned short* hsrc = hb + (size_t)(mt * 128 + r) * 256 + sc * 8;

  // B staging: 2 gl_lds/wave/stage (units wid*2, wid*2+1 of 16)
  const unsigned short* bsrc[2];
#pragma unroll
  for (int j = 0; j < 2; ++j) {
    const int u  = wid * 2 + j;                  // local unit 0..15
    const int gu = (bnn * 2 + (u >> 3)) * 8 + (u & 7);
    bsrc[j] = Bt + (size_t)gu * 12 * 512 + lane * 8;
  }
  const int adst = wid * 1024;           // wave-uniform LDS sub-offsets
  const int bd0  = (wid * 2 + 0) * 1024;
  const int bd1  = (wid * 2 + 1) * 1024;

  f32x4 acc[4][4];
#pragma unroll
  for (int m = 0; m < 4; ++m)
#pragma unroll
    for (int g = 0; g < 4; ++g)
#pragma unroll
      for (int e = 0; e < 4; ++e) acc[m][g][e] = 0.0f;

  float cvv[4][4];

  auto STAGE = [&](int T) {
    char* Ad = (char*)smem + ABUF(T % 3);
    char* Bd = (char*)smem + BBUF(T % 3);
    if (T < 4) gl16(xsrc + T * 32, Ad + adst);
    else       gl16(hsrc + (T - 4) * 32, Ad + adst);
    gl16(bsrc[0] + T * 512, Bd + bd0);
    gl16(bsrc[1] + T * 512, Bd + bd1);
  };

  auto COMPUTE = [&](int S) {
    const unsigned short* Ab = (const unsigned short*)(smem + ABUF(S % 3));
    const unsigned short* Bb = (const unsigned short*)(smem + BBUF(S % 3));
    bf16x8 afr[4], bfr[4];
#pragma unroll
    for (int m = 0; m < 4; ++m)
      afr[m] = *reinterpret_cast<const bf16x8*>(
          Ab + (wr * 64 + m * 16 + l15) * 32 + ((kq ^ sx) * 8));
#pragma unroll
    for (int g = 0; g < 4; ++g) {
      const int ub = (wcq >> 1) * 8 + g * 2 + (wcq & 1);
      bfr[g] = *reinterpret_cast<const bf16x8*>(Bb + ub * 512 + lane * 8);
    }
#pragma unroll
    for (int m = 0; m < 4; ++m)
#pragma unroll
      for (int g = 0; g < 4; ++g)
        acc[m][g] = __builtin_amdgcn_mfma_f32_16x16x32_bf16(
            afr[m], bfr[g], acc[m][g], 0, 0, 0);
  };

  // prologue: 2 stages (6 gl_lds) in flight
  STAGE(0);
  STAGE(1);

  // FIFO (3 gl_lds/stage/wave): steady VMW(3). C (16 loads) issued at end of
  // step 7 (after STAGE(9)):
  //   step 8 top: FIFO = S(8)3,S(9)3,C16 -> need S(8): VMW(19)
  //   step 9 top: FIFO = S(9)3,C16,S(10)3 -> need S(9): VMW(19)
  //   step 10 top: FIFO = C16,S(10)3,S(11)3 -> need S(10) (younger than C):
  //                VMW(3) -- drains C as a side effect
  //   step 11 top: FIFO = S(11)3 -> VMW(0). Epilogue: nothing outstanding.
#define STEP(S, KN)                                               \
  do {                                                            \
    VMW(KN);                                                      \
    __builtin_amdgcn_s_barrier();                                 \
    if ((S) + 2 < 12) STAGE((S) + 2);                             \
    if ((S) == 7) {                                               \
      const float* cb =                                           \
          Cin + ((size_t)mt * 128 + wr * 64 + kq * 4) * HDIM + ch;\
      _Pragma("unroll")                                           \
      for (int m = 0; m < 4; ++m)                                 \
        _Pragma("unroll")                                         \
        for (int e = 0; e < 4; ++e)                               \
          cvv[m][e] = __builtin_nontemporal_load(                 \
              cb + (size_t)(m * 16 + e) * HDIM);                  \
    }                                                             \
    COMPUTE(S);                                                   \
  } while (0)

  STEP(0, 3);  STEP(1, 3);  STEP(2, 3);  STEP(3, 3);
  STEP(4, 3);  STEP(5, 3);  STEP(6, 3);  STEP(7, 3);
  STEP(8, 19); STEP(9, 19); STEP(10, 3); STEP(11, 0);
#undef STEP

  // ---- epilogue: bias folded in acc; lane-local gate combine -------------
  float* op  = out + ((size_t)mt * 128 + wr * 64 + kq * 4) * HDIM + ch;
  float* op2 = op + (size_t)NROWS * HDIM;
#pragma unroll
  for (int m = 0; m < 4; ++m) {
#pragma unroll
    for (int e = 0; e < 4; ++e) {
      const float pi = acc[m][0][e];
      const float pf = acc[m][1][e];
      const float pg = acc[m][2][e];
      const float po = acc[m][3][e];
      const float ig = sigm(pi), fg = sigm(pf);
      const float gg = tanh_fast(pg), og = sigm(po);
      const float co = fg * cvv[m][e] + ig * gg;
      const float ho = og * tanh_fast(co);
      __builtin_nontemporal_store(co, op  + (size_t)(m * 16 + e) * HDIM);
      __builtin_nontemporal_store(ho, op2 + (size_t)(m * 16 + e) * HDIM);
    }
  }
}

extern "C" void kernel_launch(void* const* d_in, const int* in_sizes, int n_in,
                              void* d_out, int out_size, void* d_ws, size_t ws_size,
                              hipStream_t stream) {
  const float* x  = (const float*)d_in[0];
  const float* C  = (const float*)d_in[1];
  const float* h  = (const float*)d_in[2];
  const float* Wx = (const float*)d_in[3];
  const float* Wh = (const float*)d_in[4];
  const float* bx = (const float*)d_in[5];
  const float* bh = (const float*)d_in[6];
  float* o = (float*)d_out;
  unsigned short* ws = (unsigned short*)d_ws;   // ~98 MiB used

  prep_all<<<dim3(24768), dim3(256), 0, stream>>>(x, h, Wx, Wh, bx, bh, ws);
  lstm_main<<<dim3(4096), dim3(512), 0, stream>>>(ws, C, o);
}

// Round 20
// 189.667 us; speedup vs baseline: 2.0338x; 1.0203x over previous
//
#include <hip/hip_runtime.h>
#include <stdint.h>

// ---------------------------------------------------------------------------
// Fused LSTM cell, round 20 = r19 schedule + mfma 32x32x16 (fewer instrs/FLOP).
//  prep_all: xb[131072][128] bf16 (pad, k127=1.0 bias driver),
//            hb[131072][256] bf16, Bt repacked to 16-k fragment units:
//            unit = ((hb32*4+g)*24 + kstep16), lane: col=lane&31,
//            k=kstep*16+(lane>>5)*8+e; bias @ k==127.
//  lstm_main: 256 thr (4 waves = 2wr x 2wc), tile 128 rows x 256 gate-cols
//    (identical block footprint/grid/swizzle to r19). Per-wave 64 rows x
//    (32 H-cols x 4 gates), acc[2][4] f32x16 = 128 VGPR, (256,2) -> 2 blk/CU.
//    12 stages BK=32; per wave/stage: 6 gl_lds (2A+4B homogeneous FIFO) +
//    12 ds_read_b128 + 16 MFMA 32x32x16 (2x work of r19's 16x16 per wave).
//    A-LDS layout/staging/swizzle identical to r19; reads re-indexed
//    (row=lane&31, chunk=(kk*2+kh)^((l31>>1)&3) -- conflict-free).
//    Counted vmcnt: VMW(6) steady, C(32 full-line loads)@S==8 -> 38/38/0.
//    Epilogue: D col=lane&31 -> 32-lane full 128B store lines.
// ---------------------------------------------------------------------------

typedef short bf16x8 __attribute__((ext_vector_type(8)));
typedef float f32x16 __attribute__((ext_vector_type(16)));

#define HDIM   256
#define INDIM  100
#define NROWS  131072
// d_ws layout (ushort offsets): Bt @0 (768 KiB), xb @1 MiB, hb @34 MiB
#define BT_OFF 0
#define XB_OFF (1048576 / 2)
#define HB_OFF (35651584 / 2)
#define ABUF(b) ((b) * 8192)
#define BBUF(b) (24576 + (b) * 16384)

__device__ __forceinline__ float fexp(float x) {
  return __builtin_amdgcn_exp2f(x * 1.44269504088896340736f);
}
__device__ __forceinline__ float frcp(float x) { return __builtin_amdgcn_rcpf(x); }
__device__ __forceinline__ float sigm(float x) { return frcp(1.0f + fexp(-x)); }
__device__ __forceinline__ float tanh_fast(float x) {
  return 1.0f - 2.0f * frcp(1.0f + fexp(2.0f * x));
}
__device__ __forceinline__ unsigned short f2bf_rne(float f) {
  union { float f; uint32_t u; } v; v.f = f;
  return (unsigned short)((v.u + 0x7FFFu + ((v.u >> 16) & 1u)) >> 16);
}
__device__ __forceinline__ void gl16(const void* g, void* l) {
  __builtin_amdgcn_global_load_lds(
      (const __attribute__((address_space(1))) unsigned int*)g,
      (__attribute__((address_space(3))) unsigned int*)l, 16, 0, 0);
}
#define VMW(N) asm volatile("s_waitcnt vmcnt(" #N ")" ::: "memory")

// ---- prep: 3 jobs ----------------------------------------------------------
__global__ void prep_all(const float* __restrict__ X, const float* __restrict__ Hin,
                         const float* __restrict__ Wx, const float* __restrict__ Wh,
                         const float* __restrict__ bxp, const float* __restrict__ bhp,
                         unsigned short* __restrict__ ws) {
  const int b = blockIdx.x, tid = threadIdx.x;
  if (b < 8192) {                        // ---- x -> xb[131072][128] ----
    const int t   = b * 256 + tid;
    const int row = t >> 4, k0 = (t & 15) * 8;
    const float* xp = X + (size_t)row * INDIM;
    float4 lo = make_float4(0.f, 0.f, 0.f, 0.f);
    float4 hi = make_float4(0.f, 0.f, 0.f, 0.f);
    if (k0 + 4 <= INDIM) lo = *reinterpret_cast<const float4*>(xp + k0);
    if (k0 + 8 <= INDIM) hi = *reinterpret_cast<const float4*>(xp + k0 + 4);
    float va[8] = {lo.x, lo.y, lo.z, lo.w, hi.x, hi.y, hi.z, hi.w};
    unsigned short o[8];
#pragma unroll
    for (int e = 0; e < 8; ++e) {
      const int k = k0 + e;
      const float f = (k < INDIM) ? va[e] : (k == 127 ? 1.0f : 0.0f);
      o[e] = f2bf_rne(f);
    }
    *reinterpret_cast<bf16x8*>(ws + XB_OFF + (size_t)row * 128 + k0) =
        *reinterpret_cast<bf16x8*>(o);
  } else if (b < 24576) {                // ---- h -> hb[131072][256] ----
    const int t   = (b - 8192) * 256 + tid;
    const int row = t >> 5, k0 = (t & 31) * 8;
    const float* hp = Hin + (size_t)row * HDIM + k0;
    const float4 lo = *reinterpret_cast<const float4*>(hp);
    const float4 hi = *reinterpret_cast<const float4*>(hp + 4);
    unsigned short o[8] = {f2bf_rne(lo.x), f2bf_rne(lo.y), f2bf_rne(lo.z),
                           f2bf_rne(lo.w), f2bf_rne(hi.x), f2bf_rne(hi.y),
                           f2bf_rne(hi.z), f2bf_rne(hi.w)};
    *reinterpret_cast<bf16x8*>(ws + HB_OFF + (size_t)row * 256 + k0) =
        *reinterpret_cast<bf16x8*>(o);
  } else {                               // ---- W -> Bt blob, 16-k units ----
    const int unit = (b - 24576) * 4 + (tid >> 6);   // 0..767
    const int lane = tid & 63;
    const int kst  = unit % 24;          // 16-k step 0..23
    const int g    = (unit / 24) & 3;    // gate
    const int hb32 = unit / 96;          // 0..7 (32 H-col block)
    const int wcol = g * HDIM + hb32 * 32 + (lane & 31);
    const int kb   = kst * 16 + (lane >> 5) * 8;
    unsigned short v[8];
#pragma unroll
    for (int e = 0; e < 8; ++e) {
      const int k = kb + e;              // 0..383
      float f = 0.0f;
      if (k < INDIM)     f = Wx[(size_t)k * 1024 + wcol];
      else if (k == 127) f = bxp[wcol] + bhp[wcol];
      else if (k >= 128) f = Wh[(size_t)(k - 128) * 1024 + wcol];
      v[e] = f2bf_rne(f);
    }
    *reinterpret_cast<bf16x8*>(ws + BT_OFF + (size_t)unit * 512 + lane * 8) =
        *reinterpret_cast<bf16x8*>(v);
  }
}

// ---- main -------------------------------------------------------------------
__global__ __launch_bounds__(256, 2)
void lstm_main(const unsigned short* __restrict__ ws,
               const float* __restrict__ Cin, float* __restrict__ out)
{
  __shared__ unsigned char smem[73728];  // 3 x (8K A + 16K B)

  const int tid  = threadIdx.x;
  const int orig = blockIdx.x;           // 0..4095 (%8==0 -> bijective)
  const int lg   = ((orig & 7) << 9) | (orig >> 3);
  const int mt   = lg >> 2;              // M tile 0..1023 (128 rows)
  const int bnn  = lg & 3;               // N tile 0..3 (64 H-cols)

  const int lane = tid & 63;
  const int l31  = lane & 31;
  const int kh   = lane >> 5;            // k-half of fragment
  const int wid  = tid >> 6;             // 0..3
  const int wr   = wid >> 1;             // 0..1: 64-row group
  const int wc   = wid & 1;              // 0..1: 32-hcol half
  const int ch   = bnn * 64 + wc * 32 + l31;
  const int sx   = (l31 >> 1) & 3;       // read-side XOR (== (row>>1)&3)

  const unsigned short* xb = ws + XB_OFF;
  const unsigned short* hb = ws + HB_OFF;
  const unsigned short* Bt = ws + BT_OFF;

  // A staging: 2 gl_lds/wave/stage (layout/swizzle identical to r19)
  const unsigned short* xsrc[2];
  const unsigned short* hsrc[2];
#pragma unroll
  for (int j = 0; j < 2; ++j) {
    const int ci = (wid * 2 + j) * 64 + lane;      // 0..511
    const int r  = ci >> 2;                        // tile row 0..127
    const int sc = (ci & 3) ^ ((r >> 1) & 3);      // pre-swizzled chunk
    xsrc[j] = xb + (size_t)(mt * 128 + r) * 128 + sc * 8;
    hsrc[j] = hb + (size_t)(mt * 128 + r) * 256 + sc * 8;
  }
  const int ad0 = (wid * 2 + 0) * 1024;
  const int ad1 = (wid * 2 + 1) * 1024;

  // B staging: 4 gl_lds/wave/stage; local unit lu = wid*4+j (0..15),
  // lu = nb*8 + g*2 + kk; global unit = ((bnn*2+nb)*4+g)*24 + 2S+kk.
  const unsigned short* bsrc[4];
#pragma unroll
  for (int j = 0; j < 4; ++j) {
    const int lu = wid * 4 + j;
    const int nb = lu >> 3, g = (lu >> 1) & 3, kk = lu & 1;
    bsrc[j] = Bt + ((size_t)(((bnn * 2 + nb) * 4 + g) * 24) + kk) * 512 +
              lane * 8;
  }

  f32x16 acc[2][4];                      // [m][gate], 128 VGPR
#pragma unroll
  for (int m = 0; m < 2; ++m)
#pragma unroll
    for (int g = 0; g < 4; ++g)
#pragma unroll
      for (int e = 0; e < 16; ++e) acc[m][g][e] = 0.0f;

  float cvv[2][16];

  auto STAGE = [&](int T) {
    char* Ad = (char*)smem + ABUF(T % 3);
    char* Bd = (char*)smem + BBUF(T % 3);
    if (T < 4) {
      gl16(xsrc[0] + T * 32, Ad + ad0);
      gl16(xsrc[1] + T * 32, Ad + ad1);
    } else {
      gl16(hsrc[0] + (T - 4) * 32, Ad + ad0);
      gl16(hsrc[1] + (T - 4) * 32, Ad + ad1);
    }
#pragma unroll
    for (int j = 0; j < 4; ++j)
      gl16(bsrc[j] + T * 1024, Bd + (wid * 4 + j) * 1024);
  };

  auto COMPUTE = [&](int S) {
    const unsigned short* Ab = (const unsigned short*)(smem + ABUF(S % 3));
    const unsigned short* Bb = (const unsigned short*)(smem + BBUF(S % 3));
#pragma unroll
    for (int kk = 0; kk < 2; ++kk) {
      bf16x8 afr[2], bfr[4];
#pragma unroll
      for (int m = 0; m < 2; ++m) {
        const int row   = wr * 64 + m * 32 + l31;
        const int chunk = (kk * 2 + kh) ^ sx;
        afr[m] = *reinterpret_cast<const bf16x8*>(Ab + row * 32 + chunk * 8);
      }
#pragma unroll
      for (int g = 0; g < 4; ++g) {
        const int u = wc * 8 + g * 2 + kk;
        bfr[g] = *reinterpret_cast<const bf16x8*>(Bb + u * 512 + lane * 8);
      }
#pragma unroll
      for (int m = 0; m < 2; ++m)
#pragma unroll
        for (int g = 0; g < 4; ++g)
          acc[m][g] = __builtin_amdgcn_mfma_f32_32x32x16_bf16(
              afr[m], bfr[g], acc[m][g], 0, 0, 0);
    }
  };

  // prologue: 2 stages (12 gl_lds) in flight
  STAGE(0);
  STAGE(1);

  // FIFO (6 gl_lds/stage/wave): steady VMW(6). C (32 loads) issued at end of
  // step 8 (after STAGE(10)):
  //   step 9 top:  outstanding S9,S10,C        -> need S9  -> VMW(38)
  //   step 10 top: outstanding S10,C,S11       -> need S10 -> VMW(38)
  //   step 11 top: outstanding C,S11           -> need S11 -> VMW(0)
#define STEP(S, KN)                                                \
  do {                                                             \
    VMW(KN);                                                       \
    __builtin_amdgcn_s_barrier();                                  \
    if ((S) + 2 < 12) STAGE((S) + 2);                              \
    if ((S) == 8) {                                                \
      const float* cb =                                            \
          Cin + ((size_t)mt * 128 + wr * 64 + 4 * kh) * HDIM + ch; \
      _Pragma("unroll")                                            \
      for (int m = 0; m < 2; ++m)                                  \
        _Pragma("unroll")                                          \
        for (int rg = 0; rg < 16; ++rg) {                          \
          const int roff = m * 32 + (rg & 3) + 8 * (rg >> 2);      \
          cvv[m][rg] = __builtin_nontemporal_load(                 \
              cb + (size_t)roff * HDIM);                           \
        }                                                          \
    }                                                              \
    COMPUTE(S);                                                    \
  } while (0)

  STEP(0, 6);  STEP(1, 6);  STEP(2, 6);  STEP(3, 6);
  STEP(4, 6);  STEP(5, 6);  STEP(6, 6);  STEP(7, 6);
  STEP(8, 6);  STEP(9, 38); STEP(10, 38); STEP(11, 0);
#undef STEP

  // ---- epilogue: bias folded in acc; lane-local gate combine --------------
  // D: col = lane&31, row = (reg&3) + 8*(reg>>2) + 4*kh (+ m*32)
  // -> 32 consecutive lanes store 128B full lines.
  float* op  = out + ((size_t)mt * 128 + wr * 64 + 4 * kh) * HDIM + ch;
  float* op2 = op + (size_t)NROWS * HDIM;
#pragma unroll
  for (int m = 0; m < 2; ++m) {
#pragma unroll
    for (int rg = 0; rg < 16; ++rg) {
      const int roff = m * 32 + (rg & 3) + 8 * (rg >> 2);
      const float pi = acc[m][0][rg];
      const float pf = acc[m][1][rg];
      const float pg = acc[m][2][rg];
      const float po = acc[m][3][rg];
      const float ig = sigm(pi), fg = sigm(pf);
      const float gg = tanh_fast(pg), og = sigm(po);
      const float co = fg * cvv[m][rg] + ig * gg;
      const float ho = og * tanh_fast(co);
      __builtin_nontemporal_store(co, op  + (size_t)roff * HDIM);
      __builtin_nontemporal_store(ho, op2 + (size_t)roff * HDIM);
    }
  }
}

extern "C" void kernel_launch(void* const* d_in, const int* in_sizes, int n_in,
                              void* d_out, int out_size, void* d_ws, size_t ws_size,
                              hipStream_t stream) {
  const float* x  = (const float*)d_in[0];
  const float* C  = (const float*)d_in[1];
  const float* h  = (const float*)d_in[2];
  const float* Wx = (const float*)d_in[3];
  const float* Wh = (const float*)d_in[4];
  const float* bx = (const float*)d_in[5];
  const float* bh = (const float*)d_in[6];
  float* o = (float*)d_out;
  unsigned short* ws = (unsigned short*)d_ws;   // ~98 MiB used

  prep_all<<<dim3(24768), dim3(256), 0, stream>>>(x, h, Wx, Wh, bx, bh, ws);
  lstm_main<<<dim3(4096), dim3(256), 0, stream>>>(ws, C, o);
}